// Round 5
// baseline (4521.176 us; speedup 1.0000x reference)
//
#include <hip/hip_runtime.h>

#define NN 100000
#define NE 1600000
#define NB 391                      // ceil(NN/256)
#define MM_BLK 3125                 // NN/32 GEMM tiles; also NE/512 edge slices
#define SC_BLK 6250                 // scatter blocks (256 edges each)
#define TS_BLK 12500                // t-scale blocks (256 float4 each)
#define SP_BLK 12500                // spmm blocks (8 rows each)
#define FIXSCALE 68719476736.0f     // 2^36
#define FIXINV   (1.0 / 68719476736.0)
#define MASK48   0xFFFFFFFFFFFFULL

// ---------------- GEMM tile body: out[32x128] = x_tile @ W (* rowscale) ----
// Ws staged in 16-row chunks: LDS = 16.5 + 8 = 24.1 KB -> 6 blocks/CU.
__device__ __forceinline__ void matmul_tile(const float* __restrict__ x,
                                            const float* __restrict__ W,
                                            float* __restrict__ out,
                                            const float* __restrict__ rowscale,
                                            int tile, int tid,
                                            float (*xs)[129], float (*Ws)[128])
{
    int r = tid & 31, cg = tid >> 5;
    float acc[16];
#pragma unroll
    for (int i = 0; i < 16; i++) acc[i] = 0.f;

#pragma unroll
    for (int i = 0; i < 4; i++) {
        int idx = tid + i * 256;
        int rr = idx >> 5;
        int c4 = (idx & 31) << 2;
        *(float4*)&xs[rr][c4] =
            *(const float4*)(x + (size_t)(tile * 32 + rr) * 128 + c4);
    }

#pragma unroll
    for (int kc = 0; kc < 8; kc++) {
        __syncthreads();
#pragma unroll
        for (int i = 0; i < 2; i++) {
            int idx = tid + i * 256;
            int kk = idx >> 5;
            int c4 = (idx & 31) << 2;
            *(float4*)&Ws[kk][c4] =
                *(const float4*)(W + (size_t)(kc * 16 + kk) * 128 + c4);
        }
        __syncthreads();
#pragma unroll
        for (int k = 0; k < 16; k++) {
            float xk = xs[r][kc * 16 + k];
            const float* wr = &Ws[k][cg * 16];
#pragma unroll
            for (int jj = 0; jj < 16; jj++)
                acc[jj] = fmaf(xk, wr[jj], acc[jj]);
        }
    }

    int row = tile * 32 + r;
    float sc = rowscale ? rowscale[row] : 1.0f;
    float* op = out + (size_t)row * 128 + cg * 16;
#pragma unroll
    for (int i = 0; i < 4; i++)
        *(float4*)(op + i * 4) =
            make_float4(acc[i*4] * sc, acc[i*4+1] * sc,
                        acc[i*4+2] * sc, acc[i*4+3] * sc);
}

// ---------------- kernel 1: FUSED (homogeneous blocks) ---------------------
// Each of 3125 blocks: (A) one GEMM tile of t = node_feats @ W1 (all the
// barriers live here), then (B) its 512-edge slice: weight + one packed 64b
// atomic per direction. Atomics are issued AFTER the last barrier so no
// vmcnt(0) barrier-drain stalls them; cohort k's GEMM overlaps cohort k-1's
// atomic drain -> the ~150us atomic wall hides the whole GEMM.
__global__ __launch_bounds__(256) void fused1_kernel(
        const float* __restrict__ ef,
        const float* __restrict__ W_ef,
        const float* __restrict__ b_ef,
        const int* __restrict__ src,
        const int* __restrict__ dst,
        float* __restrict__ w_raw,
        unsigned short* __restrict__ pos_e,
        unsigned long long* __restrict__ outp,
        unsigned long long* __restrict__ inp,
        const float* __restrict__ node_feats,
        const float* __restrict__ W1,
        float* __restrict__ t_buf)
{
    __shared__ float xs[32][129];     // +1 pad: kills stride-128 bank conflict
    __shared__ float Ws[16][128];
    int tid = threadIdx.x;

    matmul_tile(node_feats, W1, t_buf, nullptr, blockIdx.x, tid, xs, Ws);

    // ---- edge slice: e0 and e0+256 ----
    int e0 = blockIdx.x * 512 + tid;
    unsigned long long old[2];
#pragma unroll
    for (int q = 0; q < 2; q++) {
        int e = e0 + q * 256;
        const float4* p = (const float4*)(ef + (size_t)e * 16);
        float acc = b_ef[0];
#pragma unroll
        for (int i = 0; i < 4; i++) {
            float4 v = p[i];
            acc += v.x * W_ef[i*4+0] + v.y * W_ef[i*4+1]
                 + v.z * W_ef[i*4+2] + v.w * W_ef[i*4+3];
        }
        w_raw[e] = acc;
        unsigned long long pk = (1ULL << 48) |
            (unsigned long long)(acc * FIXSCALE);
        atomicAdd(&outp[src[e]], pk);
        old[q] = atomicAdd(&inp[dst[e]], pk);
    }
#pragma unroll
    for (int q = 0; q < 2; q++)
        pos_e[e0 + q * 256] = (unsigned short)(old[q] >> 48);
}

// ---------------- kernel 2: combined per-node factors + block sums ---------
// fo = norm_out*rsqrt(dout_w) (folded into t rows), fi = norm_in*rsqrt(din_w)
// (folded into spmm epilogue). CSR weights stay raw.
__global__ __launch_bounds__(256) void node_norm_kernel(
        const unsigned long long* __restrict__ outp,
        const unsigned long long* __restrict__ inp,
        float* __restrict__ fo, float* __restrict__ fi,
        int* __restrict__ blk_sums)
{
    __shared__ int red[256];
    int t = threadIdx.x;
    int n = blockIdx.x * 256 + t;
    int din = 0;
    if (n < NN) {
        unsigned long long po = outp[n], pi = inp[n];
        int dout = (int)(po >> 48);
        din = (int)(pi >> 48);
        float wo = (float)((double)(po & MASK48) * FIXINV);
        float wi = (float)((double)(pi & MASK48) * FIXINV);
        float no = 1.0f / sqrtf((float)(dout > 1 ? dout : 1));
        float ni = 1.0f / sqrtf((float)(din  > 1 ? din  : 1));
        fo[n] = (wo > 0.f) ? no / sqrtf(wo) : 0.f;
        fi[n] = (wi > 0.f) ? ni / sqrtf(wi) : 0.f;
    }
    red[t] = din;
    __syncthreads();
#pragma unroll
    for (int s = 128; s > 0; s >>= 1) {
        if (t < s) red[t] += red[t + s];
        __syncthreads();
    }
    if (t == 0) blk_sums[blockIdx.x] = red[0];
}

// ---------------- kernel 3a: exclusive scan of 391 block sums --------------
__global__ void scan_blk_kernel(const int* __restrict__ blk_sums,
                                int* __restrict__ blk_off)
{
    __shared__ int s[512];
    int t = threadIdx.x;
    int v = (t < NB) ? blk_sums[t] : 0;
    s[t] = v;
    __syncthreads();
    for (int o = 1; o < 512; o <<= 1) {
        int u = (t >= o) ? s[t - o] : 0;
        __syncthreads();
        s[t] += u;
        __syncthreads();
    }
    if (t < NB) blk_off[t] = s[t] - v;   // exclusive
}

// ---------------- kernel 3b: block-local scan -> row_ptr -------------------
__global__ __launch_bounds__(256) void row_ptr_kernel(
        const unsigned long long* __restrict__ inp,
        const int* __restrict__ blk_off,
        int* __restrict__ row_ptr)
{
    __shared__ int s[256];
    int t = threadIdx.x;
    int n = blockIdx.x * 256 + t;
    int d = (n < NN) ? (int)(inp[n] >> 48) : 0;
    s[t] = d;
    __syncthreads();
    for (int o = 1; o < 256; o <<= 1) {
        int u = (t >= o) ? s[t - o] : 0;
        __syncthreads();
        s[t] += u;
        __syncthreads();
    }
    if (n < NN) {
        int rp = blk_off[blockIdx.x] + s[t] - d;   // exclusive
        row_ptr[n] = rp;
        if (n == NN - 1) row_ptr[NN] = rp + d;     // == NE
    }
}

// ---------------- kernel 4: CSR scatter (raw weights) + t row-scale by fo --
// Two roles, no LDS, tiny VGPR -> full occupancy for both.
__global__ void scatter_scale_kernel(const float* __restrict__ w_raw,
                                     const unsigned short* __restrict__ pos_e,
                                     const int* __restrict__ src,
                                     const int* __restrict__ dst,
                                     const int* __restrict__ row_ptr,
                                     int2* __restrict__ csr,
                                     float* __restrict__ t,
                                     const float* __restrict__ fo)
{
    int tid = threadIdx.x;
    if (blockIdx.x < SC_BLK) {
        int e = blockIdx.x * 256 + tid;            // SC_BLK*256 == NE exactly
        int d = dst[e];
        int pos = row_ptr[d] + (int)pos_e[e];
        csr[pos] = make_int2(src[e], __float_as_int(w_raw[e]));
    } else {
        int idx = (blockIdx.x - SC_BLK) * 256 + tid;   // float4 index < 3.2M
        int row = idx >> 5;                            // 32 float4 per row
        float f = fo[row];
        float4* p = (float4*)t + idx;
        float4 v = *p;
        v.x *= f; v.y *= f; v.z *= f; v.w *= f;
        *p = v;
    }
}

// ---------------- kernel 5: standalone GEMM (layer 2), fo folded in --------
__global__ __launch_bounds__(256) void matmul_kernel(
        const float* __restrict__ x,
        const float* __restrict__ W,
        const float* __restrict__ fo,
        float* __restrict__ out)
{
    __shared__ float xs[32][129];
    __shared__ float Ws[16][128];
    matmul_tile(x, W, out, fo, blockIdx.x, threadIdx.x, xs, Ws);
}

// ---------------- kernel 6: CSR SpMM, 2 rows/wave, float4/lane -------------
// 32 lanes per row (float4 = full 128 cols), 2 rows per wave: one 512B
// gather per half-wave -> VMEM instructions and wave count halved vs
// float2/64-lane. csr entries preloaded coalesced, broadcast via width-32
// shfl (ds_bpermute); 8-deep unroll keeps 8 gathers in flight per half.
template <bool RELU>
__global__ __launch_bounds__(256) void spmm_kernel(
        const float* __restrict__ t,
        const int* __restrict__ row_ptr,
        const int2* __restrict__ csr,
        const float* __restrict__ fi,
        const float* __restrict__ bias,
        float* __restrict__ out)
{
    int tid = threadIdx.x;
    int lane = tid & 63;
    int l32 = lane & 31;
    int row = blockIdx.x * 8 + ((tid >> 6) << 1) + (lane >> 5);  // < NN always
    int start = row_ptr[row], end = row_ptr[row + 1];
    float4 acc = make_float4(0.f, 0.f, 0.f, 0.f);
    const float* tb = t + l32 * 4;
    for (int base = start; base < end; base += 32) {
        int idx = base + l32;
        int2 pr = (idx < end) ? csr[idx] : make_int2(0, 0);
        int cnt = end - base; if (cnt > 32) cnt = 32;
        int cnt8 = (cnt + 7) & ~7;
        for (int j = 0; j < cnt8; j += 8) {
#pragma unroll
            for (int u = 0; u < 8; u++) {
                int s = __shfl(pr.x, j + u, 32);
                float w = __int_as_float(__shfl(pr.y, j + u, 32));
                float4 hv = *(const float4*)(tb + ((size_t)s << 7));
                acc.x = fmaf(w, hv.x, acc.x);
                acc.y = fmaf(w, hv.y, acc.y);
                acc.z = fmaf(w, hv.z, acc.z);
                acc.w = fmaf(w, hv.w, acc.w);
            }
        }
    }
    float f = fi[row];
    float4 b4 = *(const float4*)(bias + l32 * 4);
    float4 o;
    o.x = fmaf(acc.x, f, b4.x);
    o.y = fmaf(acc.y, f, b4.y);
    o.z = fmaf(acc.z, f, b4.z);
    o.w = fmaf(acc.w, f, b4.w);
    if (RELU) {
        o.x = o.x > 0.f ? o.x : 0.f;
        o.y = o.y > 0.f ? o.y : 0.f;
        o.z = o.z > 0.f ? o.z : 0.f;
        o.w = o.w > 0.f ? o.w : 0.f;
    }
    *(float4*)(out + (size_t)row * 128 + l32 * 4) = o;
}

// ---------------------------------------------------------------------------
extern "C" void kernel_launch(void* const* d_in, const int* in_sizes, int n_in,
                              void* d_out, int out_size, void* d_ws, size_t ws_size,
                              hipStream_t stream)
{
    const float* node_feats = (const float*)d_in[0];
    const float* edge_feats = (const float*)d_in[1];
    const float* W_ef       = (const float*)d_in[2];
    const float* b_ef       = (const float*)d_in[3];
    const float* W1         = (const float*)d_in[4];
    const float* b1         = (const float*)d_in[5];
    const float* W2         = (const float*)d_in[6];
    const float* b2         = (const float*)d_in[7];
    const int*   src        = (const int*)d_in[8];
    const int*   dst        = (const int*)d_in[9];
    float* out = (float*)d_out;

    char* ws = (char*)d_ws;
    size_t off = 0;
    auto alloc = [&](size_t bytes) {
        off = (off + 255) & ~(size_t)255;
        void* p = ws + off;
        off += bytes;
        return p;
    };

    float* w_raw = (float*)alloc((size_t)NE * 4);
    unsigned short* pos_e = (unsigned short*)alloc((size_t)NE * 2);
    unsigned long long* outp = (unsigned long long*)alloc((size_t)NN * 16);
    unsigned long long* inp  = outp + NN;
    float* fo       = (float*)alloc((size_t)NN * 4);
    float* fi       = (float*)alloc((size_t)NN * 4);
    int*   blk_sums = (int*)alloc((size_t)NB * 4);
    int*   blk_off  = (int*)alloc((size_t)NB * 4);
    int*   row_ptr  = (int*)alloc((size_t)(NN + 1) * 4);
    int2*  csr      = (int2*)alloc((size_t)NE * 8);
    float* t_buf    = (float*)alloc((size_t)NN * 128 * 4);
    float* h_buf    = (float*)alloc((size_t)NN * 128 * 4);

    hipMemsetAsync(outp, 0, (size_t)NN * 16, stream);

    // GEMM1 + edge atomic pipeline, homogeneous blocks (GEMM-first)
    fused1_kernel<<<MM_BLK, 256, 0, stream>>>(
        edge_feats, W_ef, b_ef, src, dst, w_raw, pos_e, outp, inp,
        node_feats, W1, t_buf);

    node_norm_kernel<<<NB, 256, 0, stream>>>(outp, inp, fo, fi, blk_sums);

    scan_blk_kernel<<<1, 512, 0, stream>>>(blk_sums, blk_off);

    row_ptr_kernel<<<NB, 256, 0, stream>>>(inp, blk_off, row_ptr);

    // CSR scatter (raw weights) + fo row-scale of t_buf in one dispatch
    scatter_scale_kernel<<<SC_BLK + TS_BLK, 256, 0, stream>>>(
        w_raw, pos_e, src, dst, row_ptr, csr, t_buf, fo);

    // layer 1 aggregate (+ReLU), fi in epilogue
    spmm_kernel<true><<<SP_BLK, 256, 0, stream>>>(
        t_buf, row_ptr, csr, fi, b1, h_buf);

    // layer 2: GEMM (fo folded) then aggregate
    matmul_kernel<<<MM_BLK, 256, 0, stream>>>(h_buf, W2, fo, t_buf);
    spmm_kernel<false><<<SP_BLK, 256, 0, stream>>>(
        t_buf, row_ptr, csr, fi, b2, out);
}